// Round 7
// baseline (557.087 us; speedup 1.0000x reference)
//
#include <hip/hip_runtime.h>
#include <hip/hip_bf16.h>
#include <hip/hip_cooperative_groups.h>

namespace cg = cooperative_groups;

typedef unsigned short u16;
typedef unsigned int   u32;
typedef __attribute__((ext_vector_type(8))) short short8;
typedef __attribute__((ext_vector_type(4))) float f32x4;

#define B_   2
#define L_   2048
#define CDIM 384
#define DI   768
#define DXZ  1536
#define DTR  24
#define DS   16
#define NDBC 56
#define NC   32
#define TC   64
#define TL   32
#define EPSV 1e-5f

#define OFFW_WIN  0
#define OFFW_WXP  589824
#define OFFW_WOUT 632832
#define TOTW      927744

__device__ __forceinline__ float bf2f(u16 u) {
    union { u32 i; float f; } v; v.i = ((u32)u) << 16; return v.f;
}
__device__ __forceinline__ u16 f2bf(float f) {
    union { float f; u32 i; } v; v.f = f;
    u32 x = v.i;
    u32 r = (x + 0x7FFFu + ((x >> 16) & 1u)) >> 16;
    return (u16)r;
}

struct P {
    const float *x, *ln1w, *ln1b, *ln2w, *ln2b, *win, *cw, *cb, *wxp, *wdt, *bdt, *alog, *Dw, *wout;
    u16 *wbf, *xn, *xz, *ubf, *ym;
    float *dbc, *chA, *chB, *hin, *om, *out;
};

__global__ __launch_bounds__(256, 1) void mamba_mega(P p) {
    __shared__ char sbuf[53248];
    float* tile  = (float*)sbuf;                 // [384][33]
    float* red1  = tile + 384 * 33;              // [8][32]
    float* red2  = red1 + 256;                   // [8][32]
    float* mu_s  = red2 + 256;                   // [32]
    float* rs_s  = mu_s + 32;                    // [32]

    cg::grid_group grid = cg::this_grid();
    const int tid = threadIdx.x, blk = blockIdx.x;
    const int wave = tid >> 6, lane = tid & 63;
    const int r = lane & 15, q = lane >> 4;
    short8 zf;
#pragma unroll
    for (int e = 0; e < 8; e++) zf[e] = 0;

    // ======== S0: LN1 (blocks 0..127) + weight convert (blocks 128..255) ========
    if (blk >= 128) {
        int base = (blk - 128) * 256 + tid;
        for (int e = base; e < TOTW; e += 128 * 256) {
            float v;
            if (e < OFFW_WXP)       v = p.win[e];
            else if (e < OFFW_WOUT) v = p.wxp[e - OFFW_WXP];
            else                    v = p.wout[e - OFFW_WOUT];
            p.wbf[e] = f2bf(v);
        }
    } else {
        int b = blk >> 6;
        int l0 = (blk & 63) * TL;
        int cg_ = tid >> 5, li = tid & 31;
        const float* xp = p.x + (size_t)b * CDIM * L_ + l0 + li;
        float s = 0.f, s2 = 0.f;
#pragma unroll
        for (int c = cg_; c < CDIM; c += 8) {
            float v = xp[(size_t)c * L_];
            tile[c * 33 + li] = v;
            s += v; s2 += v * v;
        }
        red1[cg_ * 32 + li] = s; red2[cg_ * 32 + li] = s2;
        __syncthreads();
        if (tid < TL) {
            float ts = 0.f, ts2 = 0.f;
#pragma unroll
            for (int g = 0; g < 8; g++) { ts += red1[g * 32 + tid]; ts2 += red2[g * 32 + tid]; }
            float mu = ts / CDIM;
            float var = ts2 / CDIM - mu * mu;
            mu_s[tid] = mu; rs_s[tid] = rsqrtf(var + EPSV);
        }
        __syncthreads();
#pragma unroll
        for (int rr = 0; rr < 8; rr++) {
            int l = wave * 8 + rr;
            float mu = mu_s[l], rs = rs_s[l];
            u16* op = p.xn + (size_t)(b * L_ + l0 + l) * CDIM;
#pragma unroll
            for (int j = 0; j < 6; j++) {
                int c = lane + 64 * j;
                float t = (tile[c * 33 + l] - mu) * rs * p.ln1w[c] + p.ln1b[c];
                op[c] = f2bf(t);
            }
        }
    }
    grid.sync();

    // ======== S1: in_proj GEMM  xz = xn @ win^T  (4096x1536, K=384) ========
    {
        const u16* wb = p.wbf + OFFW_WIN;
        int wm = wave & 1, wn = wave >> 1;
        for (int t = blk; t < 384; t += 256) {
            int tm = t & 31, tn = t >> 5;
            int m0 = (tm * 2 + wm) * 64, n0 = (tn * 2 + wn) * 64;
            f32x4 acc[4][4];
#pragma unroll
            for (int i = 0; i < 4; i++)
#pragma unroll
                for (int j = 0; j < 4; j++)
#pragma unroll
                    for (int g = 0; g < 4; g++) acc[i][j][g] = 0.f;
#pragma unroll
            for (int k0 = 0; k0 < 384; k0 += 32) {
                short8 af[4], bf[4];
                int ka = k0 + q * 8;
#pragma unroll
                for (int i = 0; i < 4; i++) {
                    af[i] = *(const short8*)(p.xn + (size_t)(m0 + i * 16 + r) * 384 + ka);
                    bf[i] = *(const short8*)(wb + (size_t)(n0 + i * 16 + r) * 384 + ka);
                }
#pragma unroll
                for (int i = 0; i < 4; i++)
#pragma unroll
                    for (int j = 0; j < 4; j++)
                        acc[i][j] = __builtin_amdgcn_mfma_f32_16x16x32_bf16(af[i], bf[j], acc[i][j], 0, 0, 0);
            }
#pragma unroll
            for (int i = 0; i < 4; i++)
#pragma unroll
                for (int j = 0; j < 4; j++) {
                    int col = n0 + j * 16 + r;
#pragma unroll
                    for (int g = 0; g < 4; g++)
                        p.xz[(size_t)(m0 + i * 16 + q * 4 + g) * DXZ + col] = f2bf(acc[i][j][g]);
                }
        }
    }
    grid.sync();

    // ======== S2: depthwise causal conv(4) + SiLU -> ubf ========
    for (int u = blk; u < 768; u += 256) {
        int d = (u >> 8) * 256 + tid;
        int m0 = (u & 255) * 16;
        int l0 = m0 & (L_ - 1);
        float4 c4 = ((const float4*)p.cw)[d];
        float bias = p.cb[d];
        float w0, w1, w2;
        if (l0 == 0) { w0 = w1 = w2 = 0.f; }
        else {
            w0 = bf2f(p.xz[(size_t)(m0 - 3) * DXZ + d]);
            w1 = bf2f(p.xz[(size_t)(m0 - 2) * DXZ + d]);
            w2 = bf2f(p.xz[(size_t)(m0 - 1) * DXZ + d]);
        }
#pragma unroll
        for (int i = 0; i < 16; i++) {
            int m = m0 + i;
            float cur = bf2f(p.xz[(size_t)m * DXZ + d]);
            float acc = bias + w0 * c4.x + w1 * c4.y + w2 * c4.z + cur * c4.w;
            float sg = 1.f / (1.f + __expf(-acc));
            p.ubf[(size_t)m * DI + d] = f2bf(acc * sg);
            w0 = w1; w1 = w2; w2 = cur;
        }
    }
    grid.sync();

    // ======== S3: x_proj GEMM  dbc = u @ wxp^T (4096x56, K=768); 1 block = 16 rows ========
    {
        const u16* wb = p.wbf + OFFW_WXP;
        int m0 = blk * 16, n0 = wave * 16;
        f32x4 acc;
#pragma unroll
        for (int g = 0; g < 4; g++) acc[g] = 0.f;
        int nr = n0 + r;
#pragma unroll 4
        for (int k0 = 0; k0 < DI; k0 += 32) {
            int ka = k0 + q * 8;
            short8 af = *(const short8*)(p.ubf + (size_t)(m0 + r) * DI + ka);
            short8 bf = (nr < NDBC) ? *(const short8*)(wb + (size_t)nr * DI + ka) : zf;
            acc = __builtin_amdgcn_mfma_f32_16x16x32_bf16(af, bf, acc, 0, 0, 0);
        }
        if (nr < NDBC) {
#pragma unroll
            for (int g = 0; g < 4; g++)
                p.dbc[(size_t)(m0 + q * 4 + g) * NDBC + nr] = acc[g];
        }
    }
    grid.sync();

    // ======== S4: scan pass 1 (delta fused), NC=32 chunks of 64 ========
    {
        int idx = blk * 256 + tid;
        if (idx < B_ * NC * DI) {
            int d = idx % DI;
            int t_ = idx / DI;                    // b*NC + chunk
            int b = t_ >> 5, chunk = t_ & 31;
            float a[DS], ap[DS], bv[DS], wdt[DTR];
#pragma unroll
            for (int s = 0; s < DS; s++) { a[s] = -__expf(p.alog[d * DS + s]); ap[s] = 1.f; bv[s] = 0.f; }
#pragma unroll
            for (int k = 0; k < DTR; k++) wdt[k] = p.wdt[d * DTR + k];
            float bd = p.bdt[d];
            int t0 = b * L_ + chunk * TC;
            for (int t = t0; t < t0 + TC; t++) {
                const float* row = p.dbc + (size_t)t * NDBC;
                float acc = bd;
#pragma unroll
                for (int k = 0; k < DTR; k++) acc += row[k] * wdt[k];
                float dd = (acc > 20.f) ? acc : __logf(1.f + __expf(acc));
                float du = dd * bf2f(p.ubf[(size_t)t * DI + d]);
#pragma unroll
                for (int s = 0; s < DS; s++) {
                    float dA = __expf(dd * a[s]);
                    bv[s] = dA * bv[s] + du * row[DTR + s];
                    ap[s] *= dA;
                }
            }
            float* pa = p.chA + ((size_t)t_ * DI + d) * DS;
            float* pb = p.chB + ((size_t)t_ * DI + d) * DS;
#pragma unroll
            for (int s = 0; s < DS; s++) { pa[s] = ap[s]; pb[s] = bv[s]; }
        }
    }
    grid.sync();

    // ======== S5: scan mid — compose chunks ========
    {
        int idx = blk * 256 + tid;
        if (idx < B_ * DI * DS) {
            int b = idx / (DI * DS);
            int rem = idx % (DI * DS);
            float h = 0.f;
#pragma unroll 4
            for (int c = 0; c < NC; c++) {
                size_t off = ((size_t)(b * NC + c) * DI) * DS + rem;
                p.hin[off] = h;
                h = p.chA[off] * h + p.chB[off];
            }
        }
    }
    grid.sync();

    // ======== S6: scan pass 2 — replay + u*D + silu(z) -> ym ========
    {
        int idx = blk * 256 + tid;
        if (idx < B_ * NC * DI) {
            int d = idx % DI;
            int t_ = idx / DI;
            int b = t_ >> 5, chunk = t_ & 31;
            float a[DS], h[DS], wdt[DTR];
#pragma unroll
            for (int s = 0; s < DS; s++) a[s] = -__expf(p.alog[d * DS + s]);
#pragma unroll
            for (int k = 0; k < DTR; k++) wdt[k] = p.wdt[d * DTR + k];
            float bd = p.bdt[d];
            const float* hp = p.hin + ((size_t)t_ * DI + d) * DS;
#pragma unroll
            for (int s = 0; s < DS; s++) h[s] = hp[s];
            float dD = p.Dw[d];
            int t0 = b * L_ + chunk * TC;
            for (int t = t0; t < t0 + TC; t++) {
                const float* row = p.dbc + (size_t)t * NDBC;
                float acc = bd;
#pragma unroll
                for (int k = 0; k < DTR; k++) acc += row[k] * wdt[k];
                float dd = (acc > 20.f) ? acc : __logf(1.f + __expf(acc));
                float uu = bf2f(p.ubf[(size_t)t * DI + d]);
                float du = dd * uu;
                float y = 0.f;
#pragma unroll
                for (int s = 0; s < DS; s++) {
                    float dA = __expf(dd * a[s]);
                    h[s] = dA * h[s] + du * row[DTR + s];
                    y += h[s] * row[DTR + DS + s];
                }
                float z = bf2f(p.xz[(size_t)t * DXZ + DI + d]);
                float sg = 1.f / (1.f + __expf(-z));
                p.ym[(size_t)t * DI + d] = f2bf((y + uu * dD) * (z * sg));
            }
        }
    }
    grid.sync();

    // ======== S7: out_proj GEMM om = ym @ wout^T (4096x384, K=768), 16x64 wave-tiles ========
    {
        const u16* wb = p.wbf + OFFW_WOUT;
        int gw = blk * 4 + wave;
        for (int t = gw; t < 1536; t += 1024) {
            int m0 = (t & 255) * 16, n0 = (t >> 8) * 64;
            f32x4 acc[4];
#pragma unroll
            for (int j = 0; j < 4; j++)
#pragma unroll
                for (int g = 0; g < 4; g++) acc[j][g] = 0.f;
#pragma unroll 4
            for (int k0 = 0; k0 < DI; k0 += 32) {
                int ka = k0 + q * 8;
                short8 af = *(const short8*)(p.ym + (size_t)(m0 + r) * DI + ka);
#pragma unroll
                for (int j = 0; j < 4; j++) {
                    short8 bf = *(const short8*)(wb + (size_t)(n0 + j * 16 + r) * DI + ka);
                    acc[j] = __builtin_amdgcn_mfma_f32_16x16x32_bf16(af, bf, acc[j], 0, 0, 0);
                }
            }
#pragma unroll
            for (int j = 0; j < 4; j++) {
                int col = n0 + j * 16 + r;
#pragma unroll
                for (int g = 0; g < 4; g++)
                    p.om[(size_t)(m0 + q * 4 + g) * CDIM + col] = acc[j][g];
            }
        }
    }
    grid.sync();

    // ======== S8: LN2 over (x + om), fp32 c-major store (blocks 0..127) ========
    if (blk < 128) {
        int b = blk >> 6;
        int l0 = (blk & 63) * TL;
        int cg_ = tid >> 5, li = tid & 31;
        const float* xp = p.x + (size_t)b * CDIM * L_ + l0 + li;
#pragma unroll
        for (int c = cg_; c < CDIM; c += 8) tile[c * 33 + li] = xp[(size_t)c * L_];
        __syncthreads();
#pragma unroll
        for (int rr = 0; rr < 8; rr++) {
            int l = wave * 8 + rr;
            const float* op = p.om + (size_t)(b * L_ + l0 + l) * CDIM;
            float s = 0.f, s2 = 0.f;
#pragma unroll
            for (int j = 0; j < 6; j++) {
                int c = lane + 64 * j;
                float t = tile[c * 33 + l] + op[c];
                tile[c * 33 + l] = t;
                s += t; s2 += t * t;
            }
#pragma unroll
            for (int off = 32; off > 0; off >>= 1) { s += __shfl_xor(s, off); s2 += __shfl_xor(s2, off); }
            if (lane == 0) {
                float mu = s / CDIM;
                float var = s2 / CDIM - mu * mu;
                mu_s[l] = mu; rs_s[l] = rsqrtf(var + EPSV);
            }
        }
        __syncthreads();
        float* outp = p.out + (size_t)b * CDIM * L_ + l0 + li;
        float mu = mu_s[li], rs = rs_s[li];
#pragma unroll
        for (int c = cg_; c < CDIM; c += 8) {
            float t = (tile[c * 33 + li] - mu) * rs * p.ln2w[c] + p.ln2b[c];
            outp[(size_t)c * L_] = t;
        }
    }
}

extern "C" void kernel_launch(void* const* d_in, const int* in_sizes, int n_in,
                              void* d_out, int out_size, void* d_ws, size_t ws_size,
                              hipStream_t stream) {
    char* ws = (char*)d_ws;
    P p;
    p.x    = (const float*)d_in[0];
    p.ln1w = (const float*)d_in[1];
    p.ln1b = (const float*)d_in[2];
    p.ln2w = (const float*)d_in[3];
    p.ln2b = (const float*)d_in[4];
    p.win  = (const float*)d_in[5];
    p.cw   = (const float*)d_in[6];
    p.cb   = (const float*)d_in[7];
    p.wxp  = (const float*)d_in[8];
    p.wdt  = (const float*)d_in[9];
    p.bdt  = (const float*)d_in[10];
    p.alog = (const float*)d_in[11];
    p.Dw   = (const float*)d_in[12];
    p.wout = (const float*)d_in[13];
    p.wbf  = (u16*)(ws + 0);                  // 1,855,488 B
    p.xn   = (u16*)(ws + 1855488);            // 4096*384 bf16
    p.xz   = (u16*)(ws + 5001216);            // 4096*1536 bf16
    p.ubf  = (u16*)(ws + 17584128);           // 4096*768 bf16
    p.dbc  = (float*)(ws + 23875584);         // 4096*56 f32
    p.chA  = (float*)(ws + 24793088);         // 2*32*768*16 f32 = 3,145,728 B
    p.chB  = (float*)(ws + 27938816);
    p.hin  = (float*)(ws + 31084544);
    p.ym   = (u16*)(ws + 34230272);           // 4096*768 bf16
    p.om   = (float*)(ws + 40521728);         // 4096*384 f32
    p.out  = (float*)d_out;

    void* args[] = { &p };
    hipLaunchCooperativeKernel((const void*)mamba_mega, dim3(256), dim3(256), args, 0, stream);
}

// Round 8
// 264.486 us; speedup vs baseline: 2.1063x; 2.1063x over previous
//
#include <hip/hip_runtime.h>
#include <hip/hip_bf16.h>

typedef unsigned short u16;
typedef unsigned int   u32;
typedef __attribute__((ext_vector_type(8))) short short8;
typedef __attribute__((ext_vector_type(4))) float f32x4;

#define B_   2
#define L_   2048
#define CDIM 384
#define DI   768
#define DXZ  1536
#define DTR  24
#define DS   16
#define NDBC 56
#define NC   64
#define TC   32
#define TL   32
#define EPSV 1e-5f

#define OFFW_WIN  0
#define OFFW_WXP  589824
#define OFFW_WOUT 632832
#define TOTW      927744

__device__ __forceinline__ float bf2f(u16 u) {
    union { u32 i; float f; } v; v.i = ((u32)u) << 16; return v.f;
}
__device__ __forceinline__ u16 f2bf(float f) {
    union { float f; u32 i; } v; v.f = f;
    u32 x = v.i;
    u32 r = (x + 0x7FFFu + ((x >> 16) & 1u)) >> 16;
    return (u16)r;
}

// ---- LN1 (blocks 0..127) + weight conversion (blocks 128..255), one dispatch ----
__global__ __launch_bounds__(256) void ln1_convert(const float* __restrict__ x,
                                                   const float* __restrict__ w,
                                                   const float* __restrict__ bb,
                                                   u16* __restrict__ xn,
                                                   const float* __restrict__ win,
                                                   const float* __restrict__ wxp,
                                                   const float* __restrict__ wout,
                                                   u16* __restrict__ wdst) {
    __shared__ float tile[CDIM][TL + 1];
    __shared__ float red_s[8][TL];
    __shared__ float red_s2[8][TL];
    __shared__ float mu_s[TL], rs_s[TL];
    int tid = threadIdx.x, blk = blockIdx.x;
    if (blk >= 128) {
        int base = (blk - 128) * 256 + tid;
        for (int e = base; e < TOTW; e += 128 * 256) {
            float v;
            if (e < OFFW_WXP)       v = win[e];
            else if (e < OFFW_WOUT) v = wxp[e - OFFW_WXP];
            else                    v = wout[e - OFFW_WOUT];
            wdst[e] = f2bf(v);
        }
        return;
    }
    int b = blk >> 6;
    int l0 = (blk & 63) * TL;
    int cg = tid >> 5, li = tid & 31;
    const float* xp = x + (size_t)b * CDIM * L_ + l0 + li;
    float s = 0.f, s2 = 0.f;
#pragma unroll
    for (int c = cg; c < CDIM; c += 8) {           // coalesced along l
        float v = xp[(size_t)c * L_];
        tile[c][li] = v;
        s += v; s2 += v * v;
    }
    red_s[cg][li] = s; red_s2[cg][li] = s2;
    __syncthreads();
    if (tid < TL) {
        float ts = 0.f, ts2 = 0.f;
#pragma unroll
        for (int g = 0; g < 8; g++) { ts += red_s[g][tid]; ts2 += red_s2[g][tid]; }
        float mu = ts / CDIM;
        float var = ts2 / CDIM - mu * mu;
        mu_s[tid] = mu; rs_s[tid] = rsqrtf(var + EPSV);
    }
    __syncthreads();
    int wv = tid >> 6, lane = tid & 63;
#pragma unroll
    for (int r = 0; r < 8; r++) {
        int l = wv * 8 + r;
        float mu = mu_s[l], rs = rs_s[l];
        u16* op = xn + (size_t)(b * L_ + l0 + l) * CDIM;
#pragma unroll
        for (int j = 0; j < 6; j++) {
            int c = lane + 64 * j;
            float t = (tile[c][l] - mu) * rs * w[c] + bb[c];
            op[c] = f2bf(t);
        }
    }
}

// ---- in_proj GEMM: 128x128 block (2x2 waves of 64x64), K=384 compile-time ----
template<int KN>
__global__ __launch_bounds__(256) void gemm_in(const u16* __restrict__ A,
                                               const u16* __restrict__ Bm,
                                               u16* __restrict__ Cp, int Nn) {
    int wave = threadIdx.x >> 6, lane = threadIdx.x & 63;
    int wm = wave & 1, wn = wave >> 1;
    int m0 = (blockIdx.x * 2 + wm) * 64;
    int n0 = (blockIdx.y * 2 + wn) * 64;
    int r = lane & 15, q = lane >> 4;
    f32x4 acc[4][4];
#pragma unroll
    for (int i = 0; i < 4; i++)
#pragma unroll
        for (int j = 0; j < 4; j++)
#pragma unroll
            for (int g = 0; g < 4; g++) acc[i][j][g] = 0.f;
#pragma unroll
    for (int k0 = 0; k0 < KN; k0 += 32) {
        short8 af[4], bf[4];
        int ka = k0 + q * 8;
#pragma unroll
        for (int i = 0; i < 4; i++) {
            af[i] = *(const short8*)(A + (size_t)(m0 + i * 16 + r) * KN + ka);
            bf[i] = *(const short8*)(Bm + (size_t)(n0 + i * 16 + r) * KN + ka);
        }
#pragma unroll
        for (int i = 0; i < 4; i++)
#pragma unroll
            for (int j = 0; j < 4; j++)
                acc[i][j] = __builtin_amdgcn_mfma_f32_16x16x32_bf16(af[i], bf[j], acc[i][j], 0, 0, 0);
    }
#pragma unroll
    for (int i = 0; i < 4; i++)
#pragma unroll
        for (int j = 0; j < 4; j++) {
            int col = n0 + j * 16 + r;
#pragma unroll
            for (int g = 0; g < 4; g++)
                Cp[(size_t)(m0 + i * 16 + q * 4 + g) * Nn + col] = f2bf(acc[i][j][g]);
        }
}

// ---- depthwise causal conv (width 4) + bias + SiLU, sliding window ----
__global__ __launch_bounds__(256) void conv_silu(const u16* __restrict__ xz,
                                                 const float* __restrict__ cw,
                                                 const float* __restrict__ cb,
                                                 u16* __restrict__ ubf) {
    int d = blockIdx.y * 256 + threadIdx.x;
    int m0 = blockIdx.x * 16;
    int l0 = m0 & (L_ - 1);
    float4 c4 = ((const float4*)cw)[d];
    float bias = cb[d];
    float w0, w1, w2;
    if (l0 == 0) { w0 = w1 = w2 = 0.f; }
    else {
        w0 = bf2f(xz[(size_t)(m0 - 3) * DXZ + d]);
        w1 = bf2f(xz[(size_t)(m0 - 2) * DXZ + d]);
        w2 = bf2f(xz[(size_t)(m0 - 1) * DXZ + d]);
    }
#pragma unroll
    for (int i = 0; i < 16; i++) {
        int m = m0 + i;
        float cur = bf2f(xz[(size_t)m * DXZ + d]);
        float acc = bias + w0 * c4.x + w1 * c4.y + w2 * c4.z + cur * c4.w;
        float sg = 1.f / (1.f + __expf(-acc));
        ubf[(size_t)m * DI + d] = f2bf(acc * sg);
        w0 = w1; w1 = w2; w2 = cur;
    }
}

// ---- x_proj GEMM: 1 wave = 16x64 tile (N=56 guard), K=768 ----
template<int KN>
__global__ __launch_bounds__(64) void gemm_xp(const u16* __restrict__ A,
                                              const u16* __restrict__ Bm,
                                              float* __restrict__ Cp) {
    int lane = threadIdx.x;
    int m0 = blockIdx.x * 16;
    int r = lane & 15, q = lane >> 4;
    f32x4 acc[4];
#pragma unroll
    for (int j = 0; j < 4; j++)
#pragma unroll
        for (int g = 0; g < 4; g++) acc[j][g] = 0.f;
    short8 zf;
#pragma unroll
    for (int e = 0; e < 8; e++) zf[e] = 0;
#pragma unroll
    for (int k0 = 0; k0 < KN; k0 += 32) {
        int ka = k0 + q * 8;
        short8 af = *(const short8*)(A + (size_t)(m0 + r) * KN + ka);
        short8 bf[4];
#pragma unroll
        for (int j = 0; j < 4; j++) {
            int n = j * 16 + r;
            bf[j] = (n < NDBC) ? *(const short8*)(Bm + (size_t)n * KN + ka) : zf;
        }
#pragma unroll
        for (int j = 0; j < 4; j++)
            acc[j] = __builtin_amdgcn_mfma_f32_16x16x32_bf16(af, bf[j], acc[j], 0, 0, 0);
    }
#pragma unroll
    for (int j = 0; j < 4; j++) {
        int col = j * 16 + r;
        if (col < NDBC) {
#pragma unroll
            for (int g = 0; g < 4; g++)
                Cp[(size_t)(m0 + q * 4 + g) * NDBC + col] = acc[j][g];
        }
    }
}

// -------- scan pass 1 (delta fused): chunk-local affine coefficients --------
__global__ __launch_bounds__(256) void scan_pass1(const u16* __restrict__ ubf,
                                                  const float* __restrict__ dbc,
                                                  const float* __restrict__ alogf,
                                                  const float* __restrict__ wdtf,
                                                  const float* __restrict__ bdtf,
                                                  float* __restrict__ chA,
                                                  float* __restrict__ chB) {
    int bc = blockIdx.x;                      // b*NC + chunk, NC=64
    int b = bc >> 6, chunk = bc & 63;
    int d = blockIdx.y * 256 + threadIdx.x;
    float a[DS], ap[DS], bv[DS], wdt[DTR];
#pragma unroll
    for (int s = 0; s < DS; s++) { a[s] = -__expf(alogf[d * DS + s]); ap[s] = 1.f; bv[s] = 0.f; }
#pragma unroll
    for (int k = 0; k < DTR; k++) wdt[k] = wdtf[d * DTR + k];
    float bd = bdtf[d];
    int t0 = b * L_ + chunk * TC;
#pragma unroll 2
    for (int t = t0; t < t0 + TC; t++) {
        const float* row = dbc + (size_t)t * NDBC;
        float acc = bd;
#pragma unroll
        for (int k = 0; k < DTR; k++) acc += row[k] * wdt[k];
        float dd = (acc > 20.f) ? acc : __logf(1.f + __expf(acc));
        float du = dd * bf2f(ubf[(size_t)t * DI + d]);
#pragma unroll
        for (int s = 0; s < DS; s++) {
            float dA = __expf(dd * a[s]);
            bv[s] = dA * bv[s] + du * row[DTR + s];
            ap[s] *= dA;
        }
    }
    float* pa = chA + ((size_t)bc * DI + d) * DS;
    float* pb = chB + ((size_t)bc * DI + d) * DS;
#pragma unroll
    for (int s = 0; s < DS; s++) { pa[s] = ap[s]; pb[s] = bv[s]; }
}

// -------- scan mid: per (b,d,s) scalar chain over chunks, coalesced --------
__global__ __launch_bounds__(256) void scan_mid(const float* __restrict__ chA,
                                                const float* __restrict__ chB,
                                                float* __restrict__ hin) {
    int idx = blockIdx.x * 256 + threadIdx.x; // 0..24575 = b*(DI*DS) + d*DS + s
    int b = idx / (DI * DS);
    int rem = idx - b * (DI * DS);
    float h = 0.f;
#pragma unroll 4
    for (int c = 0; c < NC; c++) {
        size_t off = ((size_t)(b * NC + c) * DI) * DS + rem;
        hin[off] = h;
        h = chA[off] * h + chB[off];
    }
}

// -------- scan pass 2 (delta fused): replay with h_in; +u*D, *silu(z) --------
__global__ __launch_bounds__(256) void scan_pass2(const u16* __restrict__ ubf,
                                                  const float* __restrict__ dbc,
                                                  const float* __restrict__ alogf,
                                                  const float* __restrict__ wdtf,
                                                  const float* __restrict__ bdtf,
                                                  const float* __restrict__ hin,
                                                  const float* __restrict__ Dwf,
                                                  const u16* __restrict__ xz,
                                                  u16* __restrict__ ym) {
    int bc = blockIdx.x;
    int b = bc >> 6, chunk = bc & 63;
    int d = blockIdx.y * 256 + threadIdx.x;
    float a[DS], h[DS], wdt[DTR];
#pragma unroll
    for (int s = 0; s < DS; s++) a[s] = -__expf(alogf[d * DS + s]);
#pragma unroll
    for (int k = 0; k < DTR; k++) wdt[k] = wdtf[d * DTR + k];
    float bd = bdtf[d];
    const float* hp = hin + ((size_t)bc * DI + d) * DS;
#pragma unroll
    for (int s = 0; s < DS; s++) h[s] = hp[s];
    float dD = Dwf[d];
    int t0 = b * L_ + chunk * TC;
#pragma unroll 2
    for (int t = t0; t < t0 + TC; t++) {
        const float* row = dbc + (size_t)t * NDBC;
        float acc = bd;
#pragma unroll
        for (int k = 0; k < DTR; k++) acc += row[k] * wdt[k];
        float dd = (acc > 20.f) ? acc : __logf(1.f + __expf(acc));
        float uu = bf2f(ubf[(size_t)t * DI + d]);
        float du = dd * uu;
        float y = 0.f;
#pragma unroll
        for (int s = 0; s < DS; s++) {
            float dA = __expf(dd * a[s]);
            h[s] = dA * h[s] + du * row[DTR + s];
            y += h[s] * row[DTR + DS + s];
        }
        float z = bf2f(xz[(size_t)t * DXZ + DI + d]);
        float sg = 1.f / (1.f + __expf(-z));
        ym[(size_t)t * DI + d] = f2bf((y + uu * dD) * (z * sg));
    }
}

// ---- fused out_proj GEMM + LN2: block = 64 complete rows of om ----
// Phase A: 4 waves, wave w computes rows m0..m0+63 x cols w*96..w*96+95 -> LDS bf16.
// Phase B: LN2 over (x + om_row) with coalesced c-major load/store of x/out.
#define CS_STRIDE 390
__global__ __launch_bounds__(256) void out_ln2(const u16* __restrict__ ym,
                                               const u16* __restrict__ woutb,
                                               const float* __restrict__ x,
                                               const float* __restrict__ w,
                                               const float* __restrict__ bb,
                                               float* __restrict__ out) {
    __shared__ u16 cs[64 * CS_STRIDE];          // 49,920 B
    __shared__ float ps[4][64], ps2[4][64];
    __shared__ float mu_s[64], rs_s[64];
    int tid = threadIdx.x;
    int wave = tid >> 6, lane = tid & 63;
    int r = lane & 15, q = lane >> 4;
    int m0 = blockIdx.x * 64;                    // 64 blocks
    // Phase A: GEMM 64 x 96 per wave
    f32x4 acc[4][6];
#pragma unroll
    for (int i = 0; i < 4; i++)
#pragma unroll
        for (int j = 0; j < 6; j++)
#pragma unroll
            for (int g = 0; g < 4; g++) acc[i][j][g] = 0.f;
#pragma unroll 2
    for (int k0 = 0; k0 < DI; k0 += 32) {
        int ka = k0 + q * 8;
        short8 af[4], bf[6];
#pragma unroll
        for (int i = 0; i < 4; i++)
            af[i] = *(const short8*)(ym + (size_t)(m0 + i * 16 + r) * DI + ka);
#pragma unroll
        for (int j = 0; j < 6; j++)
            bf[j] = *(const short8*)(woutb + (size_t)(wave * 96 + j * 16 + r) * DI + ka);
#pragma unroll
        for (int i = 0; i < 4; i++)
#pragma unroll
            for (int j = 0; j < 6; j++)
                acc[i][j] = __builtin_amdgcn_mfma_f32_16x16x32_bf16(af[i], bf[j], acc[i][j], 0, 0, 0);
    }
#pragma unroll
    for (int i = 0; i < 4; i++)
#pragma unroll
        for (int j = 0; j < 6; j++) {
            int col = wave * 96 + j * 16 + r;
#pragma unroll
            for (int g = 0; g < 4; g++)
                cs[(i * 16 + q * 4 + g) * CS_STRIDE + col] = f2bf(acc[i][j][g]);
        }
    __syncthreads();
    // Phase B: LN2. thread (cgr, li): row li, cols cgr::4
    int li = tid & 63, cgr = tid >> 6;
    int rowg = m0 + li;
    int b = rowg >> 11, l = rowg & (L_ - 1);
    const float* xcol = x + (size_t)b * CDIM * L_ + l;
    float s = 0.f, s2 = 0.f;
#pragma unroll
    for (int c = cgr; c < CDIM; c += 4) {
        float t = bf2f(cs[li * CS_STRIDE + c]) + xcol[(size_t)c * L_];
        s += t; s2 += t * t;
    }
    ps[cgr][li] = s; ps2[cgr][li] = s2;
    __syncthreads();
    if (tid < 64) {
        float ts = ps[0][tid] + ps[1][tid] + ps[2][tid] + ps[3][tid];
        float ts2 = ps2[0][tid] + ps2[1][tid] + ps2[2][tid] + ps2[3][tid];
        float mu = ts / CDIM;
        float var = ts2 / CDIM - mu * mu;
        mu_s[tid] = mu; rs_s[tid] = rsqrtf(var + EPSV);
    }
    __syncthreads();
    float mu = mu_s[li], rs = rs_s[li];
    float* op = out + (size_t)b * CDIM * L_ + l;
#pragma unroll
    for (int c = cgr; c < CDIM; c += 4) {
        float t = bf2f(cs[li * CS_STRIDE + c]) + xcol[(size_t)c * L_];
        op[(size_t)c * L_] = (t - mu) * rs * w[c] + bb[c];
    }
}

extern "C" void kernel_launch(void* const* d_in, const int* in_sizes, int n_in,
                              void* d_out, int out_size, void* d_ws, size_t ws_size,
                              hipStream_t stream) {
    const float* x    = (const float*)d_in[0];
    const float* ln1w = (const float*)d_in[1];
    const float* ln1b = (const float*)d_in[2];
    const float* ln2w = (const float*)d_in[3];
    const float* ln2b = (const float*)d_in[4];
    const float* win  = (const float*)d_in[5];
    const float* cw   = (const float*)d_in[6];
    const float* cb   = (const float*)d_in[7];
    const float* wxp  = (const float*)d_in[8];
    const float* wdt  = (const float*)d_in[9];
    const float* bdt  = (const float*)d_in[10];
    const float* alog = (const float*)d_in[11];
    const float* Dw   = (const float*)d_in[12];
    const float* wout = (const float*)d_in[13];

    char* ws = (char*)d_ws;
    u16*   wbf   = (u16*)(ws + 0);
    u16*   win_b  = wbf + OFFW_WIN;
    u16*   wxp_b  = wbf + OFFW_WXP;
    u16*   wout_b = wbf + OFFW_WOUT;
    u16*   xn    = (u16*)(ws + 1855488);
    u16*   xz    = (u16*)(ws + 5001216);
    u16*   ubf   = (u16*)(ws + 17584128);
    float* dbc   = (float*)(ws + 23875584);
    float* chA   = (float*)(ws + 24793088);   // 2*64*768*16 f32
    float* chB   = (float*)(ws + 31084544);
    float* hin   = (float*)(ws + 37376000);
    u16*   ym    = (u16*)(ws + 43667456);

    ln1_convert<<<dim3(256), 256, 0, stream>>>(x, ln1w, ln1b, xn, win, wxp, wout, wbf);
    gemm_in<384><<<dim3(32, 12), 256, 0, stream>>>(xn, win_b, xz, DXZ);
    conv_silu<<<dim3(256, 3), 256, 0, stream>>>(xz, cw, cb, ubf);
    gemm_xp<768><<<dim3(256), 64, 0, stream>>>(ubf, wxp_b, dbc);
    scan_pass1<<<dim3(128, 3), 256, 0, stream>>>(ubf, dbc, alog, wdt, bdt, chA, chB);
    scan_mid<<<96, 256, 0, stream>>>(chA, chB, hin);
    scan_pass2<<<dim3(128, 3), 256, 0, stream>>>(ubf, dbc, alog, wdt, bdt, hin, Dw, xz, ym);
    out_ln2<<<dim3(64), 256, 0, stream>>>(ym, wout_b, x, ln2w, ln2b, (float*)d_out);
}